// Round 2
// baseline (31.918 us; speedup 1.0000x reference)
//
#include <hip/hip_runtime.h>
#include <hip/hip_bf16.h>

using floatx4 = __attribute__((ext_vector_type(4))) float;
using shortx8 = __attribute__((ext_vector_type(8))) short;

constexpr int M = 32, N = 4096, K = 4096;
constexpr int SPLITK = 32;
constexpr int KC = K / SPLITK;   // 128
constexpr int NIT = KC / 32;     // 4 k-steps of 32, fully preloaded

// init: out = bias (poison-safe re-init every call), x -> bf16 staged in ws
__global__ __launch_bounds__(256) void init_kernel(
    const float* __restrict__ x, const float* __restrict__ bias,
    float* __restrict__ out, short* __restrict__ xbf)
{
    int i = blockIdx.x * blockDim.x + threadIdx.x;
    if (i < M * N) out[i] = bias[i & (N - 1)];
    if (i < M * K) {
        __hip_bfloat16 h = __float2bfloat16(x[i]);
        xbf[i] = *reinterpret_cast<short*>(&h);
    }
}

// Each wave: 16 W-rows x full batch(32), K-chunk of KC. All global loads for
// the chunk issued up front (max MLP), then dequant+MFMA phase. Split-K atomics.
template<bool XBF16>
__global__ __launch_bounds__(256) void gemm_kernel(
    const float* __restrict__ W, const float* __restrict__ scales,
    const short* __restrict__ xbf, const float* __restrict__ xf32,
    const float* __restrict__ tscale, float* __restrict__ out)
{
    const int lane = threadIdx.x & 63;
    const int wave = threadIdx.x >> 6;
    const int o0 = blockIdx.x * 64 + wave * 16;
    const int k0 = blockIdx.y * KC;

    const int row = lane & 15;   // o-offset for W frag; b-offset for x frag
    const int kg  = lane >> 4;   // k subgroup (8 elems each)

    const float* wp = W + (size_t)(o0 + row) * K + k0 + kg * 8;
    // block index = o*(K/16) + k/16 ; a lane's 8 elems sit in ONE scale block
    const float* sp = scales + (size_t)(o0 + row) * (K / 16) + (k0 >> 4) + (kg >> 1);
    const short* xp0 = xbf + (size_t)row * K + k0 + kg * 8;
    const short* xp1 = xbf + (size_t)(row + 16) * K + k0 + kg * 8;

    floatx4 acc0 = {0.f, 0.f, 0.f, 0.f};
    floatx4 acc1 = {0.f, 0.f, 0.f, 0.f};

    if constexpr (XBF16) {
        // ---- issue ALL global loads for this wave's chunk up front ----
        floatx4 w0[NIT], w1[NIT];
        #pragma unroll
        for (int i = 0; i < NIT; ++i) {
            w0[i] = *reinterpret_cast<const floatx4*>(wp + i * 32);
            w1[i] = *reinterpret_cast<const floatx4*>(wp + i * 32 + 4);
        }
        float s[NIT];
        #pragma unroll
        for (int i = 0; i < NIT; ++i) s[i] = sp[2 * i];
        shortx8 xa[NIT], xb[NIT];
        #pragma unroll
        for (int i = 0; i < NIT; ++i) {
            xa[i] = *reinterpret_cast<const shortx8*>(xp0 + i * 32);
            xb[i] = *reinterpret_cast<const shortx8*>(xp1 + i * 32);
        }
        const float rt = 1.0f / tscale[0];

        // ---- compute phase: dequant in-register, 2 MFMA per k-step ----
        #pragma unroll
        for (int i = 0; i < NIT; ++i) {
            const float rs = rt / s[i];          // w/(s*t) == w * (rt/s)
            shortx8 wf;
            float wv[8] = {w0[i][0], w0[i][1], w0[i][2], w0[i][3],
                           w1[i][0], w1[i][1], w1[i][2], w1[i][3]};
            #pragma unroll
            for (int j = 0; j < 8; ++j) {
                __hip_bfloat16 h = __float2bfloat16(wv[j] * rs);
                wf[j] = *reinterpret_cast<short*>(&h);
            }
            acc0 = __builtin_amdgcn_mfma_f32_16x16x32_bf16(xa[i], wf, acc0, 0, 0, 0);
            acc1 = __builtin_amdgcn_mfma_f32_16x16x32_bf16(xb[i], wf, acc1, 0, 0, 0);
        }
    } else {
        // fallback: x as f32 (no workspace) — rolled loop
        const float* xf0 = xf32 + (size_t)row * K + k0 + kg * 8;
        const float* xf1 = xf32 + (size_t)(row + 16) * K + k0 + kg * 8;
        const float rt = 1.0f / tscale[0];
        for (int i = 0; i < NIT; ++i) {
            floatx4 w0 = *reinterpret_cast<const floatx4*>(wp + i * 32);
            floatx4 w1 = *reinterpret_cast<const floatx4*>(wp + i * 32 + 4);
            float s = sp[2 * i];
            shortx8 xa, xb, wf;
            float av[8] = {xf0[i*32+0], xf0[i*32+1], xf0[i*32+2], xf0[i*32+3],
                           xf0[i*32+4], xf0[i*32+5], xf0[i*32+6], xf0[i*32+7]};
            float bv[8] = {xf1[i*32+0], xf1[i*32+1], xf1[i*32+2], xf1[i*32+3],
                           xf1[i*32+4], xf1[i*32+5], xf1[i*32+6], xf1[i*32+7]};
            float wv[8] = {w0[0],w0[1],w0[2],w0[3],w1[0],w1[1],w1[2],w1[3]};
            const float rs = rt / s;
            #pragma unroll
            for (int j = 0; j < 8; ++j) {
                __hip_bfloat16 ha = __float2bfloat16(av[j]);
                __hip_bfloat16 hb = __float2bfloat16(bv[j]);
                __hip_bfloat16 hw = __float2bfloat16(wv[j] * rs);
                xa[j] = *reinterpret_cast<short*>(&ha);
                xb[j] = *reinterpret_cast<short*>(&hb);
                wf[j] = *reinterpret_cast<short*>(&hw);
            }
            acc0 = __builtin_amdgcn_mfma_f32_16x16x32_bf16(xa, wf, acc0, 0, 0, 0);
            acc1 = __builtin_amdgcn_mfma_f32_16x16x32_bf16(xb, wf, acc1, 0, 0, 0);
        }
    }

    // D[row=(lane>>4)*4+r][col=lane&15]: row = batch, col = o  -> coalesced atomics
    float* op0 = out + (size_t)(kg * 4) * N + o0 + row;
    float* op1 = out + (size_t)(16 + kg * 4) * N + o0 + row;
    #pragma unroll
    for (int r = 0; r < 4; ++r) {
        atomicAdd(op0 + (size_t)r * N, acc0[r]);
        atomicAdd(op1 + (size_t)r * N, acc1[r]);
    }
}

extern "C" void kernel_launch(void* const* d_in, const int* in_sizes, int n_in,
                              void* d_out, int out_size, void* d_ws, size_t ws_size,
                              hipStream_t stream)
{
    const float* x      = (const float*)d_in[0];
    const float* W      = (const float*)d_in[1];
    const float* tscale = (const float*)d_in[2];
    const float* scales = (const float*)d_in[3];
    const float* bias   = (const float*)d_in[4];
    float* out = (float*)d_out;
    short* xbf = (short*)d_ws;                    // needs M*K*2 = 256 KiB

    const bool use_ws = (ws_size >= (size_t)M * K * sizeof(short));

    init_kernel<<<(M * K + 255) / 256, 256, 0, stream>>>(x, bias, out, xbf);

    dim3 grid(N / 64, SPLITK);
    if (use_ws)
        gemm_kernel<true><<<grid, 256, 0, stream>>>(W, scales, xbf, x, tscale, out);
    else
        gemm_kernel<false><<<grid, 256, 0, stream>>>(W, scales, xbf, x, tscale, out);
}